// Round 6
// baseline (110.308 us; speedup 1.0000x reference)
//
#include <hip/hip_runtime.h>
#include <hip/hip_bf16.h>

#define NN     270
#define MPAD   384
#define NFEAT  4096
#define NHID   1024
#define NHEADS 8
#define NCLS   8
#define NDRUG  175
#define NMIC   95
#define LALPHA 0.2f

typedef unsigned short u16;
typedef unsigned int   u32;
typedef __attribute__((ext_vector_type(8))) short bf16x8;
typedef __attribute__((ext_vector_type(4))) short bf16x4;
typedef __attribute__((ext_vector_type(4))) float f32x4;

static __device__ __forceinline__ u16 f2bf(float f) {
  union { float f; u32 u; } v; v.f = f;
  u32 r = v.u + 0x7FFFu + ((v.u >> 16) & 1u);   // round-to-nearest-even
  return (u16)(r >> 16);
}
static __device__ __forceinline__ float bf2f(u16 b) {
  union { u32 u; float f; } v; v.u = ((u32)b) << 16;
  return v.f;
}
static __device__ __forceinline__ float wave_red(float v) {
  #pragma unroll
  for (int o = 32; o > 0; o >>= 1) v += __shfl_down(v, o, 64);
  return v;
}
// raw barrier with compiler-level memory fence (no vmcnt drain!)
static __device__ __forceinline__ void block_sync() {
  asm volatile("" ::: "memory");
  __builtin_amdgcn_s_barrier();
  asm volatile("" ::: "memory");
}
#define GLOAD16(g, l) __builtin_amdgcn_global_load_lds(                    \
    (__attribute__((address_space(1))) void*)(g),                          \
    (__attribute__((address_space(3))) void*)(l), 16, 0, 0)

// ---------------- K0: x (f32) -> xb (bf16), zero-padded to 384 rows ----------
__global__ void cvt_x(const float* __restrict__ x, u16* __restrict__ xb) {
  int i = (blockIdx.x * 256 + threadIdx.x) * 8;
  if (i >= MPAD * NFEAT) return;
  int row = i >> 12;                 // / NFEAT
  uint4 o = {0, 0, 0, 0};
  if (row < NN) {
    float4 a = *(const float4*)(x + i);
    float4 b = *(const float4*)(x + i + 4);
    o.x = (u32)f2bf(a.x) | ((u32)f2bf(a.y) << 16);
    o.y = (u32)f2bf(a.z) | ((u32)f2bf(a.w) << 16);
    o.z = (u32)f2bf(b.x) | ((u32)f2bf(b.y) << 16);
    o.w = (u32)f2bf(b.z) | ((u32)f2bf(b.w) << 16);
  }
  *(uint4*)(xb + i) = o;
}

// ---------------- K1: Hpart[ks] = x @ W[kchunk ks] (per head), bf16 partials --
// 1536 blocks = 3 m-tiles (128 rows) x 128 n-tiles (64 cols) x 4 K-chunks (K=1024).
// 48 KB LDS -> 3 blocks/CU (12 waves/CU).  XCD swizzle: the 12 blocks (3mt x 4ks)
// sharing one ntile's 1MB W slice land on the same XCD -> W re-reads hit L2.
// 256 thr = 4 waves; wave (wm,wn): rows wm*64.. (m-rep 4), cols wn*32.. (n-rep 2).
// A: global_load_lds (linear dest, source chunk-swizzle p ^= (row>>1)&3).
// W: global_load_lds f32 [k][col] -> in-LDS transpose+cvt to bf16 [kb][col] 16B
//    chunks (conflict-free b128), overlapped with previous tile's MFMAs.
// Counted vmcnt: A 2-deep, W 3-deep; A=2,W=2 loads/thread/iter; steady vmcnt(4).
__global__ __launch_bounds__(256, 3) void gemm1(const u16* __restrict__ xb,
                                                const float* __restrict__ W,
                                                u16* __restrict__ Hpart) {
  __shared__ __align__(16) u16   lA[2][128 * 32];    // 2 x 8 KB  [row][32k] swz chunks
  __shared__ __align__(16) float lWf[3][32 * 64];    // 3 x 8 KB  [k][col] linear
  __shared__ __align__(16) u32   lWbf[2][1024];      // 2 x 4 KB  [kb][col][16B]
  const int tid  = threadIdx.x;
  const int lane = tid & 63;
  const int wv   = tid >> 6;         // 0..3
  const int wm   = wv >> 1;          // 64-row band
  const int wn   = wv & 1;           // 32-col band
  // XCD-grouping swizzle (bid%8 = XCD round-robin): 192 blocks/XCD = 16 ntiles x 12
  const int bid   = blockIdx.x;
  const int xcd   = bid & 7;
  const int local = bid >> 3;        // 0..191
  const int ntile = xcd * 16 + local / 12;   // 0..127
  const int r12   = local % 12;
  const int mt    = r12 % 3;         // m-tile 0..2
  const int ks    = r12 / 3;         // K-chunk 0..3
  const int head  = ntile >> 4;
  const int jB    = (ntile & 15) * 64;

  // per-thread global staging bases (bytes)
  const char* gA0 = (const char*)xb + (size_t)(mt * 128 + (tid >> 2)) * 8192
                    + ks * 2048 + (((tid & 3) ^ ((tid >> 3) & 3)) << 4);  // src swizzle
  const char* gW0 = (const char*)W + (size_t)head * 16777216 + (size_t)ks * 4194304
                    + (tid >> 4) * 4096 + jB * 4 + ((tid & 15) << 4);

  auto issueA = [&](int j) {         // 128x32 bf16 = 8 KB -> 2 x 16B per thread
    char* l0 = (char*)&lA[j & 1][0] + tid * 16;
    const char* g0 = gA0 + j * 64;
    GLOAD16(g0, l0);                           // rows (tid>>2)
    GLOAD16(g0 + 524288, l0 + 4096);           // rows (tid>>2)+64 (swz class same)
  };
  auto issueW = [&](int j) {         // 32x64 f32 = 8 KB -> 2 x 16B per thread
    char* l0 = (char*)&lWf[j % 3][0] + tid * 16;
    const char* g0 = gW0 + j * 131072;
    GLOAD16(g0, l0);
    GLOAD16(g0 + 65536, l0 + 4096);
  };
  const int tcol = tid & 63;
  const int tkb  = tid >> 6;
  auto transposeW = [&](int j) {      // lWf[j%3] f32 [k][col] -> lWbf[j&1] bf16
    const float* wf = &lWf[j % 3][0];
    float f[8];
    #pragma unroll
    for (int q = 0; q < 8; ++q) f[q] = wf[(tkb * 8 + q) * 64 + tcol];
    uint4 o;
    o.x = (u32)f2bf(f[0]) | ((u32)f2bf(f[1]) << 16);
    o.y = (u32)f2bf(f[2]) | ((u32)f2bf(f[3]) << 16);
    o.z = (u32)f2bf(f[4]) | ((u32)f2bf(f[5]) << 16);
    o.w = (u32)f2bf(f[6]) | ((u32)f2bf(f[7]) << 16);
    *(uint4*)((char*)&lWbf[j & 1][0] + tkb * 1024 + tcol * 16) = o;
  };

  f32x4 acc[4][2];
  #pragma unroll
  for (int m = 0; m < 4; ++m)
    #pragma unroll
    for (int n = 0; n < 2; ++n) acc[m][n] = (f32x4){0.f, 0.f, 0.f, 0.f};

  // prologue FIFO: W0(2) W1(2) A0(2) A1(2) W2(2) = 10 outstanding
  issueW(0); issueW(1); issueA(0); issueA(1); issueW(2);
  asm volatile("s_waitcnt vmcnt(8)" ::: "memory");   // W0 landed
  block_sync();
  transposeW(0);
  asm volatile("s_waitcnt lgkmcnt(0)" ::: "memory");

  const int lc = lane & 15;
  const int lg = lane >> 4;
  for (int j = 0; j < 32; ++j) {
    // steady outstanding at top: [A(j):2, W(j+1):2, A(j+1):2, W(j+2):2] = 8
    if (j <= 29)      asm volatile("s_waitcnt vmcnt(4)" ::: "memory");
    else if (j == 30) asm volatile("s_waitcnt vmcnt(2)" ::: "memory");
    else              asm volatile("s_waitcnt vmcnt(0)" ::: "memory");
    block_sync();   // barrier1: A(j), Wf(j+1) visible; Wbf(j) published

    {
      const char* aB = (const char*)&lA[j & 1][0];
      const char* bB = (const char*)&lWbf[j & 1][0];
      bf16x8 bfr[2];
      #pragma unroll
      for (int n = 0; n < 2; ++n)
        bfr[n] = *(const bf16x8*)(bB + lg * 1024 + (wn * 32 + n * 16 + lc) * 16);
      #pragma unroll
      for (int m = 0; m < 4; ++m) {
        const int row = wm * 64 + m * 16 + lc;
        bf16x8 afr = *(const bf16x8*)(aB + row * 64 + ((lg ^ ((row >> 1) & 3)) << 4));
        #pragma unroll
        for (int n = 0; n < 2; ++n)
          acc[m][n] = __builtin_amdgcn_mfma_f32_16x16x32_bf16(afr, bfr[n], acc[m][n], 0, 0, 0);
      }
      if (j < 31) transposeW(j + 1);   // overlaps MFMAs; published at next barrier1
    }
    asm volatile("s_waitcnt lgkmcnt(0)" ::: "memory");
    block_sync();   // barrier2: lA[j&1] / lWf[(j+3)%3] free for refill
    if (j <= 29) issueA(j + 2);
    if (j <= 28) issueW(j + 3);
  }

  // epilogue: bf16 partials
  u16* hp = Hpart + (size_t)ks * (NN * 8192) + (size_t)(ntile * 64) + wn * 32;
  #pragma unroll
  for (int m = 0; m < 4; ++m)
    #pragma unroll
    for (int r = 0; r < 4; ++r) {
      const int row = mt * 128 + wm * 64 + m * 16 + (lg << 2) + r;
      if (row < NN) {
        #pragma unroll
        for (int n = 0; n < 2; ++n)
          hp[(size_t)row * 8192 + n * 16 + lc] = f2bf(acc[m][n][r]);
      }
    }
}

// ---------------- K2: reduce K-partials + src/dst dots + Hb (bf16) ----------
__global__ void srcdstf(const u16* __restrict__ Hp, const float* __restrict__ a_src,
                        const float* __restrict__ a_dst, u16* __restrict__ Hb,
                        float* __restrict__ srcv, float* __restrict__ dstv) {
  const int i = blockIdx.x, h = blockIdx.y;
  const int tid = threadIdx.x;
  const int j4 = tid * 4;
  const u16* base = Hp + (size_t)i * 8192 + h * 1024 + j4;
  float4 v = {0.f, 0.f, 0.f, 0.f};
  #pragma unroll
  for (int q = 0; q < 4; ++q) {
    bf16x4 p = *(const bf16x4*)(base + (size_t)q * (NN * 8192));
    v.x += bf2f((u16)p[0]); v.y += bf2f((u16)p[1]);
    v.z += bf2f((u16)p[2]); v.w += bf2f((u16)p[3]);
  }
  // Hb
  u16* hb = Hb + ((size_t)h * NN + i) * NHID + j4;
  ushort4 hv = { f2bf(v.x), f2bf(v.y), f2bf(v.z), f2bf(v.w) };
  *(ushort4*)hb = hv;
  // dots
  const float4 as4 = *(const float4*)(a_src + h * NHID + j4);
  const float4 ad4 = *(const float4*)(a_dst + h * NHID + j4);
  float s = v.x * as4.x + v.y * as4.y + v.z * as4.z + v.w * as4.w;
  float d = v.x * ad4.x + v.y * ad4.y + v.z * ad4.z + v.w * ad4.w;
  s = wave_red(s); d = wave_red(d);
  __shared__ float rb[8];
  const int lane = tid & 63, wid = tid >> 6;
  if (lane == 0) { rb[wid] = s; rb[4 + wid] = d; }
  __syncthreads();
  if (tid == 0) {
    srcv[h * NN + i] = rb[0] + rb[1] + rb[2] + rb[3];
    dstv[h * NN + i] = rb[4] + rb[5] + rb[6] + rb[7];
  }
}

// ---------------- K3a: e = exp(-leakyrelu(src_i+dst_j))*mask, rowsum ----------------
__global__ void ekern(const int* __restrict__ adj, const float* __restrict__ srcv,
                      const float* __restrict__ dstv, u16* __restrict__ eb,
                      float* __restrict__ rowsum) {
  const int i = blockIdx.x, h = blockIdx.y;
  const int n = threadIdx.x;          // 0..319
  float ev = 0.f;
  if (n < NN && adj[i * NN + n] != 0) {
    float lg = srcv[h * NN + i] + dstv[h * NN + n];
    float lr = lg > 0.f ? lg : LALPHA * lg;
    ev = expf(-lr);
  }
  u16 evb = f2bf(ev);
  eb[(size_t)h * NN * 320 + (size_t)i * 320 + n] = evb;
  float evr = wave_red(bf2f(evb));    // sum the bf16-rounded weights (consistency)
  __shared__ float rb[5];
  const int lane = threadIdx.x & 63, wid = threadIdx.x >> 6;
  if (lane == 0) rb[wid] = evr;
  __syncthreads();
  if (threadIdx.x == 0) rowsum[h * NN + i] = rb[0] + rb[1] + rb[2] + rb[3] + rb[4];
}

// ---------------- K3b: h2 = elu((e @ H) / rowsum), concat heads ----------------
__global__ __launch_bounds__(512) void gemm2(const u16* __restrict__ eb,
                                             const u16* __restrict__ Hb,
                                             const float* __restrict__ rowsum,
                                             float* __restrict__ h2) {
  __shared__ __align__(16) u16 lA[320 * 72];
  __shared__ __align__(16) u16 lB[32 * 72];
  const int tid  = threadIdx.x;
  const int lane = tid & 63;
  const int wid  = tid >> 6;
  const int wm   = wid >> 1;
  const int wn   = wid & 1;
  const int head = blockIdx.x >> 5;
  const int j0   = (blockIdx.x & 31) * 32;
  f32x4 acc[5];
  #pragma unroll
  for (int m = 0; m < 5; ++m) acc[m] = (f32x4){0.f, 0.f, 0.f, 0.f};

  for (int k0 = 0; k0 < 320; k0 += 64) {
    __syncthreads();
    #pragma unroll
    for (int it = 0; it < 5; ++it) {
      int f   = tid + it * 512;
      int row = f >> 3;
      int kc  = (f & 7) << 3;
      bf16x8 v = {0,0,0,0,0,0,0,0};
      if (row < NN) v = *(const bf16x8*)(eb + (size_t)head * NN * 320 + (size_t)row * 320 + k0 + kc);
      *(bf16x8*)(lA + row * 72 + kc) = v;
    }
    {
      int kk2 = tid >> 3;
      int jc2 = (tid & 7) << 2;
      int k   = k0 + kk2;
      u16 v0 = 0, v1 = 0, v2 = 0, v3 = 0;
      if (k < NN) {
        bf16x4 hv = *(const bf16x4*)(Hb + (size_t)head * NN * NHID + (size_t)k * NHID + j0 + jc2);
        v0 = (u16)hv[0]; v1 = (u16)hv[1]; v2 = (u16)hv[2]; v3 = (u16)hv[3];
      }
      lB[(jc2 + 0) * 72 + kk2] = v0;
      lB[(jc2 + 1) * 72 + kk2] = v1;
      lB[(jc2 + 2) * 72 + kk2] = v2;
      lB[(jc2 + 3) * 72 + kk2] = v3;
    }
    __syncthreads();
    #pragma unroll
    for (int sub = 0; sub < 2; ++sub) {
      int ksub = sub * 32 + ((lane >> 4) << 3);
      bf16x8 bfrag = *(const bf16x8*)(lB + (wn * 16 + (lane & 15)) * 72 + ksub);
      #pragma unroll
      for (int m = 0; m < 5; ++m) {
        int row = wm * 80 + m * 16 + (lane & 15);
        bf16x8 afrag = *(const bf16x8*)(lA + row * 72 + ksub);
        acc[m] = __builtin_amdgcn_mfma_f32_16x16x32_bf16(afrag, bfrag, acc[m], 0, 0, 0);
      }
    }
  }
  const int jj = j0 + wn * 16 + (lane & 15);
  #pragma unroll
  for (int m = 0; m < 5; ++m) {
    #pragma unroll
    for (int r = 0; r < 4; ++r) {
      int row = wm * 80 + m * 16 + ((lane >> 4) << 2) + r;
      if (row < NN) {
        float v = acc[m][r] / rowsum[head * NN + row];
        v = v > 0.f ? v : expm1f(v);                 // elu
        h2[(size_t)row * (NHEADS * NHID) + head * NHID + jj] = v;
      }
    }
  }
}

// ---------------- K4: layer-2 h = h2 @ W_out, plus src2/dst2 ----------------
__global__ void layer2(const float* __restrict__ h2, const float* __restrict__ Wout,
                       const float* __restrict__ aos, const float* __restrict__ aod,
                       float* __restrict__ hL2, float* __restrict__ src2,
                       float* __restrict__ dst2) {
  const int i = blockIdx.x;
  float acc[8] = {0,0,0,0,0,0,0,0};
  for (int k = threadIdx.x; k < NHEADS * NHID; k += 256) {
    float hv = h2[(size_t)i * (NHEADS * NHID) + k];
    const float4 w0 = *(const float4*)(Wout + (size_t)k * 8);
    const float4 w1 = *(const float4*)(Wout + (size_t)k * 8 + 4);
    acc[0] += hv * w0.x; acc[1] += hv * w0.y; acc[2] += hv * w0.z; acc[3] += hv * w0.w;
    acc[4] += hv * w1.x; acc[5] += hv * w1.y; acc[6] += hv * w1.z; acc[7] += hv * w1.w;
  }
  #pragma unroll
  for (int c = 0; c < 8; ++c) acc[c] = wave_red(acc[c]);
  __shared__ float rb[4][8];
  const int lane = threadIdx.x & 63, wid = threadIdx.x >> 6;
  if (lane == 0) {
    #pragma unroll
    for (int c = 0; c < 8; ++c) rb[wid][c] = acc[c];
  }
  __syncthreads();
  if (threadIdx.x == 0) {
    float s = 0.f, d = 0.f;
    #pragma unroll
    for (int c = 0; c < 8; ++c) {
      float v = rb[0][c] + rb[1][c] + rb[2][c] + rb[3][c];
      hL2[i * 8 + c] = v;
      s += v * aos[c];
      d += v * aod[c];
    }
    src2[i] = s; dst2[i] = d;
  }
}

// ---------------- K5a: layer-2 attention + aggregation + elu ----------------
__global__ void out2k(const int* __restrict__ adj, const float* __restrict__ src2,
                      const float* __restrict__ dst2, const float* __restrict__ hL2,
                      float* __restrict__ out2) {
  const int i = blockIdx.x;
  float se = 0.f, acc[8] = {0,0,0,0,0,0,0,0};
  for (int n = threadIdx.x; n < NN; n += 256) {
    if (adj[i * NN + n] != 0) {
      float lg = src2[i] + dst2[n];
      float lr = lg > 0.f ? lg : LALPHA * lg;
      float ev = expf(-lr);
      se += ev;
      #pragma unroll
      for (int c = 0; c < 8; ++c) acc[c] += ev * hL2[n * 8 + c];
    }
  }
  se = wave_red(se);
  #pragma unroll
  for (int c = 0; c < 8; ++c) acc[c] = wave_red(acc[c]);
  __shared__ float rb[4][9];
  const int lane = threadIdx.x & 63, wid = threadIdx.x >> 6;
  if (lane == 0) {
    #pragma unroll
    for (int c = 0; c < 8; ++c) rb[wid][c] = acc[c];
    rb[wid][8] = se;
  }
  __syncthreads();
  if (threadIdx.x == 0) {
    float s = rb[0][8] + rb[1][8] + rb[2][8] + rb[3][8];
    #pragma unroll
    for (int c = 0; c < 8; ++c) {
      float v = (rb[0][c] + rb[1][c] + rb[2][c] + rb[3][c]) / s;
      out2[i * 8 + c] = v > 0.f ? v : expm1f(v);
    }
  }
}

// ---------------- K5b: out = drug @ alpha1 @ mic^T ----------------
__global__ void finalk(const float* __restrict__ out2, const float* __restrict__ alpha1,
                       float* __restrict__ out) {
  int t = blockIdx.x * 256 + threadIdx.x;
  if (t >= NDRUG * NMIC) return;
  int d = t / NMIC, m = t % NMIC;
  const float* dr = out2 + d * 8;
  const float* mi = out2 + (NDRUG + m) * 8;
  float r = 0.f;
  #pragma unroll
  for (int c2 = 0; c2 < 8; ++c2) {
    float a = 0.f;
    #pragma unroll
    for (int c1 = 0; c1 < 8; ++c1) a += dr[c1] * alpha1[c1 * 8 + c2];
    r += a * mi[c2];
  }
  out[t] = r;
}

extern "C" void kernel_launch(void* const* d_in, const int* in_sizes, int n_in,
                              void* d_out, int out_size, void* d_ws, size_t ws_size,
                              hipStream_t stream) {
  const float* x      = (const float*)d_in[0];
  const int*   adj    = (const int*)d_in[1];
  const float* W      = (const float*)d_in[2];
  const float* a_src  = (const float*)d_in[3];
  const float* a_dst  = (const float*)d_in[4];
  const float* W_out  = (const float*)d_in[5];
  const float* aos    = (const float*)d_in[6];
  const float* aod    = (const float*)d_in[7];
  const float* alpha1 = (const float*)d_in[8];
  float* out = (float*)d_out;

  char* p = (char*)d_ws;
  auto take = [&](size_t bytes) {
    char* q = p;
    p += (bytes + 255) & ~(size_t)255;
    return q;
  };
  u16*   xb    = (u16*)  take((size_t)MPAD * NFEAT * 2);            // 3.15 MB
  u16*   Hpart = (u16*)  take((size_t)4 * NN * 8192 * 2);           // 17.7 MB (bf16 partials)
  u16*   Hb    = (u16*)  take((size_t)NHEADS * NN * NHID * 2);      // 4.42 MB
  float* srcv  = (float*)take((size_t)NHEADS * NN * 4);
  float* dstv  = (float*)take((size_t)NHEADS * NN * 4);
  // --- aliases into Hpart (dead after srcdstf) ---
  char*  hbase = (char*)Hpart;
  float* h2    = (float*)hbase;                                     // 8.85 MB @ +0
  u16*   eb    = (u16*)  (hbase + 10000000);                        // 1.38 MB
  float* rs    = (float*)(hbase + 11500000);
  float* hL2   = (float*)(hbase + 11600000);
  float* s2    = (float*)(hbase + 11700000);
  float* d2    = (float*)(hbase + 11800000);
  float* o2    = (float*)(hbase + 11900000);

  cvt_x<<<768, 256, 0, stream>>>(x, xb);
  gemm1<<<1536, 256, 0, stream>>>(xb, W, Hpart);
  srcdstf<<<dim3(NN, NHEADS), 256, 0, stream>>>(Hpart, a_src, a_dst, Hb, srcv, dstv);
  ekern<<<dim3(NN, NHEADS), 320, 0, stream>>>(adj, srcv, dstv, eb, rs);
  gemm2<<<256, 512, 0, stream>>>(eb, Hb, rs, h2);
  layer2<<<NN, 256, 0, stream>>>(h2, W_out, aos, aod, hL2, s2, d2);
  out2k<<<NN, 256, 0, stream>>>(adj, s2, d2, hL2, o2);
  finalk<<<65, 256, 0, stream>>>(o2, alpha1, out);
}

// Round 8
// 95.545 us; speedup vs baseline: 1.1545x; 1.1545x over previous
//
#include <hip/hip_runtime.h>
#include <hip/hip_bf16.h>

#define NN     270
#define MPAD   320
#define NFEAT  4096
#define NHID   1024
#define NHEADS 8
#define NCLS   8
#define NDRUG  175
#define NMIC   95
#define LALPHA 0.2f
#define NKS    8          // K-chunks in gemm1

typedef unsigned short u16;
typedef unsigned int   u32;
typedef __attribute__((ext_vector_type(8))) short bf16x8;
typedef __attribute__((ext_vector_type(4))) short bf16x4;
typedef __attribute__((ext_vector_type(4))) float f32x4;

static __device__ __forceinline__ u16 f2bf(float f) {
  union { float f; u32 u; } v; v.f = f;
  u32 r = v.u + 0x7FFFu + ((v.u >> 16) & 1u);   // round-to-nearest-even
  return (u16)(r >> 16);
}
static __device__ __forceinline__ float bf2f(u16 b) {
  union { u32 u; float f; } v; v.u = ((u32)b) << 16;
  return v.f;
}
static __device__ __forceinline__ float wave_red(float v) {
  #pragma unroll
  for (int o = 32; o > 0; o >>= 1) v += __shfl_down(v, o, 64);
  return v;
}
static __device__ __forceinline__ void block_sync() {
  asm volatile("" ::: "memory");
  __builtin_amdgcn_s_barrier();
  asm volatile("" ::: "memory");
}
static __device__ __forceinline__ void compiler_fence() {
  asm volatile("" ::: "memory");
}
#define GLOAD16(g, l) __builtin_amdgcn_global_load_lds(                    \
    (__attribute__((address_space(1))) void*)(g),                          \
    (__attribute__((address_space(3))) void*)(l), 16, 0, 0)

// ---------------- K0: x (f32) -> xb (bf16), zero-padded to 320 rows ----------
__global__ void cvt_x(const float* __restrict__ x, u16* __restrict__ xb) {
  int i = (blockIdx.x * 256 + threadIdx.x) * 8;
  if (i >= MPAD * NFEAT) return;
  int row = i >> 12;                 // / NFEAT
  uint4 o = {0, 0, 0, 0};
  if (row < NN) {
    float4 a = *(const float4*)(x + i);
    float4 b = *(const float4*)(x + i + 4);
    o.x = (u32)f2bf(a.x) | ((u32)f2bf(a.y) << 16);
    o.y = (u32)f2bf(a.z) | ((u32)f2bf(a.w) << 16);
    o.z = (u32)f2bf(b.x) | ((u32)f2bf(b.y) << 16);
    o.w = (u32)f2bf(b.z) | ((u32)f2bf(b.w) << 16);
  }
  *(uint4*)(xb + i) = o;
}

// ---------------- K1: Hpart[ks] = x @ W[kchunk ks], delivery-minimal --------
// 256 blocks = 32 n-tiles (BN=256 cols) x 8 K-chunks (K=512); BM=320 (full M)
// -> W staged EXACTLY once (134 MB), A staged 32x (84 MB): 218 MB total.
// 512 thr = 8 waves: (wm 0..3: 80-row band) x (wn 0..1: 128-col band), acc 5x8.
// A: global_load_lds 16B, source chunk-swizzled (p ^= (row>>1)&3), 2-deep.
// W: global f32 -> VGPR (16 coalesced dwords/thread, 2 reg sets) -> cvt ->
//    ds_write_b128 column-chunks. No lWf buffer, no LDS transpose.
// Schedule: delivery-bound -> single vmcnt(0) per iter; 16 iters.
// r7 BUGFIX: Hpart column base is ntile*256 (global col), NOT jB (within-head).
__global__ __launch_bounds__(512) void gemm1(const u16* __restrict__ xb,
                                             const float* __restrict__ W,
                                             u16* __restrict__ Hpart) {
  __shared__ __align__(16) u16 lA[2][MPAD * 32];   // 2 x 20 KB [row][64B], swz chunks
  __shared__ __align__(16) u32 lWbf[2][4096];      // 2 x 16 KB [kb(4)][col(256)][16B]
  const int tid  = threadIdx.x;
  const int lane = tid & 63;
  const int wv   = tid >> 6;
  const int wm   = wv >> 1;          // 80-row band
  const int wn   = wv & 1;           // 128-col band
  const int lc   = lane & 15;
  const int lg   = lane >> 4;
  // ks = bid&7: blocks sharing an A K-chunk land on one XCD (round-robin dispatch)
  const int ks    = blockIdx.x & 7;
  const int ntile = blockIdx.x >> 3;         // 0..31
  const int head  = ntile >> 2;
  const int jB    = (ntile & 3) * 256;       // within-head col base (for W only)

  // ---- A staging: 320x32 bf16 = 20 KB = 1280 chunks of 16B ----
  auto issueA = [&](int j) {
    char* lbase = (char*)&lA[j & 1][0];
    #pragma unroll
    for (int q = 0; q < 2; ++q) {
      int c = q * 512 + tid;
      int row = c >> 2, p = c & 3;
      const char* g = (const char*)xb + (size_t)row * 8192 + ks * 1024 + j * 64
                      + ((p ^ ((row >> 1) & 3)) << 4);
      GLOAD16(g, lbase + c * 16);
    }
    if (tid < 256) {                 // wave-uniform (waves 0-3)
      int c = 1024 + tid;
      int row = c >> 2, p = c & 3;
      const char* g = (const char*)xb + (size_t)row * 8192 + ks * 1024 + j * 64
                      + ((p ^ ((row >> 1) & 3)) << 4);
      GLOAD16(g, lbase + c * 16);
    }
  };

  // ---- W loads: thread owns col (tid&255), k-half (tid>>8): 16 k's of 1 col --
  const float* wbase = W + (size_t)head * 4194304
                       + ((size_t)ks * 512 + (size_t)(tid >> 8) * 16) * 1024
                       + jB + (tid & 255);
  #define LOADW(J, WR)                                                     \
    { const float* ws_ = wbase + (size_t)(J) * 32768;                      \
      _Pragma("unroll")                                                    \
      for (int q_ = 0; q_ < 16; ++q_) WR[q_] = ws_[(size_t)q_ * 1024]; }

  const int wcol = tid & 255;
  const int wkh  = tid >> 8;
  #define CVTW(DSTBUF, WR)                                                 \
    { u32* d_ = &lWbf[DSTBUF][0];                                          \
      _Pragma("unroll")                                                    \
      for (int i_ = 0; i_ < 2; ++i_) {                                     \
        int kb_ = wkh * 2 + i_;                                            \
        uint4 o_;                                                          \
        o_.x = (u32)f2bf(WR[i_*8+0]) | ((u32)f2bf(WR[i_*8+1]) << 16);      \
        o_.y = (u32)f2bf(WR[i_*8+2]) | ((u32)f2bf(WR[i_*8+3]) << 16);      \
        o_.z = (u32)f2bf(WR[i_*8+4]) | ((u32)f2bf(WR[i_*8+5]) << 16);      \
        o_.w = (u32)f2bf(WR[i_*8+6]) | ((u32)f2bf(WR[i_*8+7]) << 16);      \
        *(uint4*)((char*)d_ + (kb_ * 256 + wcol) * 16) = o_;               \
      } }

  f32x4 acc[5][8];
  #pragma unroll
  for (int m = 0; m < 5; ++m)
    #pragma unroll
    for (int n = 0; n < 8; ++n) acc[m][n] = (f32x4){0.f, 0.f, 0.f, 0.f};

  float wA[16], wB[16];
  // prologue: A0,A1 glds FIRST (order pinned vs plain loads), then W0,W1 regs.
  // FIFO: A0(<=3) A1(<=3) W0(16) W1(16); vmcnt(16) leaves exactly W1.
  issueA(0); issueA(1);
  compiler_fence();                  // keep plain loads below the glds intrinsics
  LOADW(0, wA); LOADW(1, wB);
  asm volatile("s_waitcnt vmcnt(16)" ::: "memory");
  CVTW(0, wA);
  asm volatile("s_waitcnt lgkmcnt(0)" ::: "memory");

  #define BODY(J, WCVT, WLOAD)                                             \
    {                                                                      \
      const int j_ = (J);                                                  \
      block_sync(); /* barrier1: lA[j&1], lWbf[j&1] published */           \
      const char* aB = (const char*)&lA[j_ & 1][0];                        \
      const char* bB = (const char*)&lWbf[j_ & 1][0];                      \
      bf16x8 bfr[8];                                                       \
      _Pragma("unroll")                                                    \
      for (int n = 0; n < 8; ++n) {                                        \
        int col = wn * 128 + n * 16 + lc;                                  \
        bfr[n] = *(const bf16x8*)(bB + ((lg * 256 + col) << 4));           \
      }                                                                    \
      _Pragma("unroll")                                                    \
      for (int m = 0; m < 5; ++m) {                                        \
        int row = wm * 80 + m * 16 + lc;                                   \
        bf16x8 afr = *(const bf16x8*)(aB + row * 64                        \
                       + ((lg ^ ((row >> 1) & 3)) << 4));                  \
        _Pragma("unroll")                                                  \
        for (int n = 0; n < 8; ++n)                                        \
          acc[m][n] = __builtin_amdgcn_mfma_f32_16x16x32_bf16(             \
              afr, bfr[n], acc[m][n], 0, 0, 0);                            \
      }                                                                    \
      asm volatile("s_waitcnt vmcnt(0)" ::: "memory");                     \
      if (j_ < 15) { CVTW((j_ + 1) & 1, WCVT); }                           \
      asm volatile("s_waitcnt lgkmcnt(0)" ::: "memory");                   \
      block_sync(); /* barrier2: lWbf[(j+1)&1] done, lA[j&1] free */       \
      if (j_ < 14) { issueA(j_ + 2); LOADW(j_ + 2, WLOAD); }               \
    }

  for (int jj = 0; jj < 16; jj += 2) {
    BODY(jj,     wB, wA);
    BODY(jj + 1, wA, wB);
  }
  #undef BODY
  #undef LOADW
  #undef CVTW

  // epilogue: bf16 partials, layout [ks][NN][8192]; global col = ntile*256 + ...
  u16* hp = Hpart + (size_t)ks * (NN * 8192) + ntile * 256 + wn * 128;
  #pragma unroll
  for (int m = 0; m < 5; ++m)
    #pragma unroll
    for (int r = 0; r < 4; ++r) {
      const int row = wm * 80 + m * 16 + (lg << 2) + r;
      if (row < NN) {
        #pragma unroll
        for (int n = 0; n < 8; ++n)
          hp[(size_t)row * 8192 + n * 16 + lc] = f2bf(acc[m][n][r]);
      }
    }
}

// ---------------- K2: reduce 8 K-partials + src/dst dots + Hb (bf16) --------
__global__ void srcdstf(const u16* __restrict__ Hp, const float* __restrict__ a_src,
                        const float* __restrict__ a_dst, u16* __restrict__ Hb,
                        float* __restrict__ srcv, float* __restrict__ dstv) {
  const int i = blockIdx.x, h = blockIdx.y;
  const int tid = threadIdx.x;
  const int j4 = tid * 4;
  const u16* base = Hp + (size_t)i * 8192 + h * 1024 + j4;
  float4 v = {0.f, 0.f, 0.f, 0.f};
  #pragma unroll
  for (int q = 0; q < NKS; ++q) {
    bf16x4 p = *(const bf16x4*)(base + (size_t)q * (NN * 8192));
    v.x += bf2f((u16)p[0]); v.y += bf2f((u16)p[1]);
    v.z += bf2f((u16)p[2]); v.w += bf2f((u16)p[3]);
  }
  u16* hb = Hb + ((size_t)h * NN + i) * NHID + j4;
  ushort4 hv = { f2bf(v.x), f2bf(v.y), f2bf(v.z), f2bf(v.w) };
  *(ushort4*)hb = hv;
  const float4 as4 = *(const float4*)(a_src + h * NHID + j4);
  const float4 ad4 = *(const float4*)(a_dst + h * NHID + j4);
  float s = v.x * as4.x + v.y * as4.y + v.z * as4.z + v.w * as4.w;
  float d = v.x * ad4.x + v.y * ad4.y + v.z * ad4.z + v.w * ad4.w;
  s = wave_red(s); d = wave_red(d);
  __shared__ float rb[8];
  const int lane = tid & 63, wid = tid >> 6;
  if (lane == 0) { rb[wid] = s; rb[4 + wid] = d; }
  __syncthreads();
  if (tid == 0) {
    srcv[h * NN + i] = rb[0] + rb[1] + rb[2] + rb[3];
    dstv[h * NN + i] = rb[4] + rb[5] + rb[6] + rb[7];
  }
}

// ---------------- K3a: e = exp(-leakyrelu(src_i+dst_j))*mask, rowsum ----------------
__global__ void ekern(const int* __restrict__ adj, const float* __restrict__ srcv,
                      const float* __restrict__ dstv, u16* __restrict__ eb,
                      float* __restrict__ rowsum) {
  const int i = blockIdx.x, h = blockIdx.y;
  const int n = threadIdx.x;          // 0..319
  float ev = 0.f;
  if (n < NN && adj[i * NN + n] != 0) {
    float lg = srcv[h * NN + i] + dstv[h * NN + n];
    float lr = lg > 0.f ? lg : LALPHA * lg;
    ev = expf(-lr);
  }
  u16 evb = f2bf(ev);
  eb[(size_t)h * NN * 320 + (size_t)i * 320 + n] = evb;
  float evr = wave_red(bf2f(evb));
  __shared__ float rb[5];
  const int lane = threadIdx.x & 63, wid = threadIdx.x >> 6;
  if (lane == 0) rb[wid] = evr;
  __syncthreads();
  if (threadIdx.x == 0) rowsum[h * NN + i] = rb[0] + rb[1] + rb[2] + rb[3] + rb[4];
}

// ---------------- K3b: h2 = elu((e @ H) / rowsum), concat heads ----------------
__global__ __launch_bounds__(512) void gemm2(const u16* __restrict__ eb,
                                             const u16* __restrict__ Hb,
                                             const float* __restrict__ rowsum,
                                             float* __restrict__ h2) {
  __shared__ __align__(16) u16 lA[320 * 72];
  __shared__ __align__(16) u16 lB[32 * 72];
  const int tid  = threadIdx.x;
  const int lane = tid & 63;
  const int wid  = tid >> 6;
  const int wm   = wid >> 1;
  const int wn   = wid & 1;
  const int head = blockIdx.x >> 5;
  const int j0   = (blockIdx.x & 31) * 32;
  f32x4 acc[5];
  #pragma unroll
  for (int m = 0; m < 5; ++m) acc[m] = (f32x4){0.f, 0.f, 0.f, 0.f};

  for (int k0 = 0; k0 < 320; k0 += 64) {
    __syncthreads();
    #pragma unroll
    for (int it = 0; it < 5; ++it) {
      int f   = tid + it * 512;
      int row = f >> 3;
      int kc  = (f & 7) << 3;
      bf16x8 v = {0,0,0,0,0,0,0,0};
      if (row < NN) v = *(const bf16x8*)(eb + (size_t)head * NN * 320 + (size_t)row * 320 + k0 + kc);
      *(bf16x8*)(lA + row * 72 + kc) = v;
    }
    {
      int kk2 = tid >> 3;
      int jc2 = (tid & 7) << 2;
      int k   = k0 + kk2;
      u16 v0 = 0, v1 = 0, v2 = 0, v3 = 0;
      if (k < NN) {
        bf16x4 hv = *(const bf16x4*)(Hb + (size_t)head * NN * NHID + (size_t)k * NHID + j0 + jc2);
        v0 = (u16)hv[0]; v1 = (u16)hv[1]; v2 = (u16)hv[2]; v3 = (u16)hv[3];
      }
      lB[(jc2 + 0) * 72 + kk2] = v0;
      lB[(jc2 + 1) * 72 + kk2] = v1;
      lB[(jc2 + 2) * 72 + kk2] = v2;
      lB[(jc2 + 3) * 72 + kk2] = v3;
    }
    __syncthreads();
    #pragma unroll
    for (int sub = 0; sub < 2; ++sub) {
      int ksub = sub * 32 + ((lane >> 4) << 3);
      bf16x8 bfrag = *(const bf16x8*)(lB + (wn * 16 + (lane & 15)) * 72 + ksub);
      #pragma unroll
      for (int m = 0; m < 5; ++m) {
        int row = wm * 80 + m * 16 + (lane & 15);
        bf16x8 afrag = *(const bf16x8*)(lA + row * 72 + ksub);
        acc[m] = __builtin_amdgcn_mfma_f32_16x16x32_bf16(afrag, bfrag, acc[m], 0, 0, 0);
      }
    }
  }
  const int jj = j0 + wn * 16 + (lane & 15);
  #pragma unroll
  for (int m = 0; m < 5; ++m) {
    #pragma unroll
    for (int r = 0; r < 4; ++r) {
      int row = wm * 80 + m * 16 + ((lane >> 4) << 2) + r;
      if (row < NN) {
        float v = acc[m][r] / rowsum[head * NN + row];
        v = v > 0.f ? v : expm1f(v);                 // elu
        h2[(size_t)row * (NHEADS * NHID) + head * NHID + jj] = v;
      }
    }
  }
}

// ---------------- K4: layer-2 h = h2 @ W_out, plus src2/dst2 ----------------
__global__ void layer2(const float* __restrict__ h2, const float* __restrict__ Wout,
                       const float* __restrict__ aos, const float* __restrict__ aod,
                       float* __restrict__ hL2, float* __restrict__ src2,
                       float* __restrict__ dst2) {
  const int i = blockIdx.x;
  float acc[8] = {0,0,0,0,0,0,0,0};
  for (int k = threadIdx.x; k < NHEADS * NHID; k += 256) {
    float hv = h2[(size_t)i * (NHEADS * NHID) + k];
    const float4 w0 = *(const float4*)(Wout + (size_t)k * 8);
    const float4 w1 = *(const float4*)(Wout + (size_t)k * 8 + 4);
    acc[0] += hv * w0.x; acc[1] += hv * w0.y; acc[2] += hv * w0.z; acc[3] += hv * w0.w;
    acc[4] += hv * w1.x; acc[5] += hv * w1.y; acc[6] += hv * w1.z; acc[7] += hv * w1.w;
  }
  #pragma unroll
  for (int c = 0; c < 8; ++c) acc[c] = wave_red(acc[c]);
  __shared__ float rb[4][8];
  const int lane = threadIdx.x & 63, wid = threadIdx.x >> 6;
  if (lane == 0) {
    #pragma unroll
    for (int c = 0; c < 8; ++c) rb[wid][c] = acc[c];
  }
  __syncthreads();
  if (threadIdx.x == 0) {
    float s = 0.f, d = 0.f;
    #pragma unroll
    for (int c = 0; c < 8; ++c) {
      float v = rb[0][c] + rb[1][c] + rb[2][c] + rb[3][c];
      hL2[i * 8 + c] = v;
      s += v * aos[c];
      d += v * aod[c];
    }
    src2[i] = s; dst2[i] = d;
  }
}

// ---------------- K5a: layer-2 attention + aggregation + elu ----------------
__global__ void out2k(const int* __restrict__ adj, const float* __restrict__ src2,
                      const float* __restrict__ dst2, const float* __restrict__ hL2,
                      float* __restrict__ out2) {
  const int i = blockIdx.x;
  float se = 0.f, acc[8] = {0,0,0,0,0,0,0,0};
  for (int n = threadIdx.x; n < NN; n += 256) {
    if (adj[i * NN + n] != 0) {
      float lg = src2[i] + dst2[n];
      float lr = lg > 0.f ? lg : LALPHA * lg;
      float ev = expf(-lr);
      se += ev;
      #pragma unroll
      for (int c = 0; c < 8; ++c) acc[c] += ev * hL2[n * 8 + c];
    }
  }
  se = wave_red(se);
  #pragma unroll
  for (int c = 0; c < 8; ++c) acc[c] = wave_red(acc[c]);
  __shared__ float rb[4][9];
  const int lane = threadIdx.x & 63, wid = threadIdx.x >> 6;
  if (lane == 0) {
    #pragma unroll
    for (int c = 0; c < 8; ++c) rb[wid][c] = acc[c];
    rb[wid][8] = se;
  }
  __syncthreads();
  if (threadIdx.x == 0) {
    float s = rb[0][8] + rb[1][8] + rb[2][8] + rb[3][8];
    #pragma unroll
    for (int c = 0; c < 8; ++c) {
      float v = (rb[0][c] + rb[1][c] + rb[2][c] + rb[3][c]) / s;
      out2[i * 8 + c] = v > 0.f ? v : expm1f(v);
    }
  }
}

// ---------------- K5b: out = drug @ alpha1 @ mic^T ----------------
__global__ void finalk(const float* __restrict__ out2, const float* __restrict__ alpha1,
                       float* __restrict__ out) {
  int t = blockIdx.x * 256 + threadIdx.x;
  if (t >= NDRUG * NMIC) return;
  int d = t / NMIC, m = t % NMIC;
  const float* dr = out2 + d * 8;
  const float* mi = out2 + (NDRUG + m) * 8;
  float r = 0.f;
  #pragma unroll
  for (int c2 = 0; c2 < 8; ++c2) {
    float a = 0.f;
    #pragma unroll
    for (int c1 = 0; c1 < 8; ++c1) a += dr[c1] * alpha1[c1 * 8 + c2];
    r += a * mi[c2];
  }
  out[t] = r;
}

extern "C" void kernel_launch(void* const* d_in, const int* in_sizes, int n_in,
                              void* d_out, int out_size, void* d_ws, size_t ws_size,
                              hipStream_t stream) {
  const float* x      = (const float*)d_in[0];
  const int*   adj    = (const int*)d_in[1];
  const float* W      = (const float*)d_in[2];
  const float* a_src  = (const float*)d_in[3];
  const float* a_dst  = (const float*)d_in[4];
  const float* W_out  = (const float*)d_in[5];
  const float* aos    = (const float*)d_in[6];
  const float* aod    = (const float*)d_in[7];
  const float* alpha1 = (const float*)d_in[8];
  float* out = (float*)d_out;

  char* p = (char*)d_ws;
  auto take = [&](size_t bytes) {
    char* q = p;
    p += (bytes + 255) & ~(size_t)255;
    return q;
  };
  u16*   xb    = (u16*)  take((size_t)MPAD * NFEAT * 2);            // 2.62 MB
  u16*   Hpart = (u16*)  take((size_t)NKS * NN * 8192 * 2);         // 35.4 MB (bf16 partials)
  u16*   Hb    = (u16*)  take((size_t)NHEADS * NN * NHID * 2);      // 4.42 MB
  float* srcv  = (float*)take((size_t)NHEADS * NN * 4);
  float* dstv  = (float*)take((size_t)NHEADS * NN * 4);
  // --- aliases into Hpart (dead after srcdstf) ---
  char*  hbase = (char*)Hpart;
  float* h2    = (float*)hbase;                                     // 8.85 MB @ +0
  u16*   eb    = (u16*)  (hbase + 10000000);                        // 1.38 MB
  float* rs    = (float*)(hbase + 11500000);
  float* hL2   = (float*)(hbase + 11600000);
  float* s2    = (float*)(hbase + 11700000);
  float* d2    = (float*)(hbase + 11800000);
  float* o2    = (float*)(hbase + 11900000);

  cvt_x<<<640, 256, 0, stream>>>(x, xb);
  gemm1<<<256, 512, 0, stream>>>(xb, W, Hpart);
  srcdstf<<<dim3(NN, NHEADS), 256, 0, stream>>>(Hpart, a_src, a_dst, Hb, srcv, dstv);
  ekern<<<dim3(NN, NHEADS), 320, 0, stream>>>(adj, srcv, dstv, eb, rs);
  gemm2<<<256, 512, 0, stream>>>(eb, Hb, rs, h2);
  layer2<<<NN, 256, 0, stream>>>(h2, W_out, aos, aod, hL2, s2, d2);
  out2k<<<NN, 256, 0, stream>>>(adj, s2, d2, hL2, o2);
  finalk<<<65, 256, 0, stream>>>(o2, alpha1, out);
}

// Round 9
// 95.015 us; speedup vs baseline: 1.1610x; 1.0056x over previous
//
#include <hip/hip_runtime.h>
#include <hip/hip_bf16.h>

#define NN     270
#define MPAD   320
#define NFEAT  4096
#define NHID   1024
#define NHEADS 8
#define NCLS   8
#define NDRUG  175
#define NMIC   95
#define LALPHA 0.2f
#define NKS    8          // K-chunks in gemm1

typedef unsigned short u16;
typedef unsigned int   u32;
typedef __attribute__((ext_vector_type(8))) short bf16x8;
typedef __attribute__((ext_vector_type(4))) short bf16x4;
typedef __attribute__((ext_vector_type(4))) float f32x4;

static __device__ __forceinline__ u16 f2bf(float f) {
  union { float f; u32 u; } v; v.f = f;
  u32 r = v.u + 0x7FFFu + ((v.u >> 16) & 1u);   // round-to-nearest-even
  return (u16)(r >> 16);
}
static __device__ __forceinline__ float bf2f(u16 b) {
  union { u32 u; float f; } v; v.u = ((u32)b) << 16;
  return v.f;
}
static __device__ __forceinline__ float wave_red(float v) {
  #pragma unroll
  for (int o = 32; o > 0; o >>= 1) v += __shfl_down(v, o, 64);
  return v;
}
static __device__ __forceinline__ void block_sync() {
  asm volatile("" ::: "memory");
  __builtin_amdgcn_s_barrier();
  asm volatile("" ::: "memory");
}
static __device__ __forceinline__ void compiler_fence() {
  asm volatile("" ::: "memory");
}
#define GLOAD16(g, l) __builtin_amdgcn_global_load_lds(                    \
    (__attribute__((address_space(1))) void*)(g),                          \
    (__attribute__((address_space(3))) void*)(l), 16, 0, 0)

// ---------------- K0: x (f32) -> xb (bf16), zero-padded to 320 rows ----------
__global__ void cvt_x(const float* __restrict__ x, u16* __restrict__ xb) {
  int i = (blockIdx.x * 256 + threadIdx.x) * 8;
  if (i >= MPAD * NFEAT) return;
  int row = i >> 12;                 // / NFEAT
  uint4 o = {0, 0, 0, 0};
  if (row < NN) {
    float4 a = *(const float4*)(x + i);
    float4 b = *(const float4*)(x + i + 4);
    o.x = (u32)f2bf(a.x) | ((u32)f2bf(a.y) << 16);
    o.y = (u32)f2bf(a.z) | ((u32)f2bf(a.w) << 16);
    o.z = (u32)f2bf(b.x) | ((u32)f2bf(b.y) << 16);
    o.w = (u32)f2bf(b.z) | ((u32)f2bf(b.w) << 16);
  }
  *(uint4*)(xb + i) = o;
}

// ---------------- K1: Hpart[ks] = x @ W[kchunk ks], counted-vmcnt pipeline ---
// Geometry (r8, kept): 256 blocks = 32 n-tiles (BN=256) x 8 K-chunks (K=512);
// BM=320 -> W staged EXACTLY once (134 MB), A 32x from L2 (84 MB).
// Schedule (new): 2-deep counted FIFO incl. the W register loads.
// Per-wave per-iter batch: [W:16 plain dwords][A: 3 glds (wv<4) / 2 (wv>=4)].
// Steady waits: pre-MFMA leave W(j+1)+A(j+1) -> vmcnt(19|18);
//               pre-CVTW leave A(j+1)       -> vmcnt(3|2);
// prologue vmcnt(22|20); vmcnt(0) only at j=15. Never drains in steady state.
__global__ __launch_bounds__(512) void gemm1(const u16* __restrict__ xb,
                                             const float* __restrict__ W,
                                             u16* __restrict__ Hpart) {
  __shared__ __align__(16) u16 lA[2][MPAD * 32];   // 2 x 20 KB [row][64B], swz chunks
  __shared__ __align__(16) u32 lWbf[2][4096];      // 2 x 16 KB [kb(4)][col(256)][16B]
  const int tid  = threadIdx.x;
  const int lane = tid & 63;
  const int wv   = tid >> 6;
  const int wm   = wv >> 1;          // 80-row band
  const int wn   = wv & 1;           // 128-col band
  const int lc   = lane & 15;
  const int lg   = lane >> 4;
  const int ks    = blockIdx.x & 7;          // same-A blocks share an XCD
  const int ntile = blockIdx.x >> 3;         // 0..31
  const int head  = ntile >> 2;
  const int jB    = (ntile & 3) * 256;       // within-head col base (W only)

  // ---- A staging: 320x32 bf16 = 20 KB = 1280 chunks of 16B ----
  auto issueA = [&](int j) {
    char* lbase = (char*)&lA[j & 1][0];
    #pragma unroll
    for (int q = 0; q < 2; ++q) {
      int c = q * 512 + tid;
      int row = c >> 2, p = c & 3;
      const char* g = (const char*)xb + (size_t)row * 8192 + ks * 1024 + j * 64
                      + ((p ^ ((row >> 1) & 3)) << 4);
      GLOAD16(g, lbase + c * 16);
    }
    if (tid < 256) {                 // waves 0-3 issue a 3rd glds
      int c = 1024 + tid;
      int row = c >> 2, p = c & 3;
      const char* g = (const char*)xb + (size_t)row * 8192 + ks * 1024 + j * 64
                      + ((p ^ ((row >> 1) & 3)) << 4);
      GLOAD16(g, lbase + c * 16);
    }
  };

  // ---- W loads: thread owns col (tid&255), k-half (tid>>8): 16 k's of 1 col --
  const float* wbase = W + (size_t)head * 4194304
                       + ((size_t)ks * 512 + (size_t)(tid >> 8) * 16) * 1024
                       + jB + (tid & 255);
  #define LOADW(J, WR)                                                     \
    { const float* ws_ = wbase + (size_t)(J) * 32768;                      \
      _Pragma("unroll")                                                    \
      for (int q_ = 0; q_ < 16; ++q_) WR[q_] = ws_[(size_t)q_ * 1024]; }

  const int wcol = tid & 255;
  const int wkh  = tid >> 8;
  #define CVTW(DSTBUF, WR)                                                 \
    { u32* d_ = &lWbf[DSTBUF][0];                                          \
      _Pragma("unroll")                                                    \
      for (int i_ = 0; i_ < 2; ++i_) {                                     \
        int kb_ = wkh * 2 + i_;                                            \
        uint4 o_;                                                          \
        o_.x = (u32)f2bf(WR[i_*8+0]) | ((u32)f2bf(WR[i_*8+1]) << 16);      \
        o_.y = (u32)f2bf(WR[i_*8+2]) | ((u32)f2bf(WR[i_*8+3]) << 16);      \
        o_.z = (u32)f2bf(WR[i_*8+4]) | ((u32)f2bf(WR[i_*8+5]) << 16);      \
        o_.w = (u32)f2bf(WR[i_*8+6]) | ((u32)f2bf(WR[i_*8+7]) << 16);      \
        *(uint4*)((char*)d_ + (kb_ * 256 + wcol) * 16) = o_;               \
      } }

  // wave-uniform counted waits (waves 0-3 have 1 extra A glds per batch)
  #define WAITV(N03, N47)                                                  \
    { if (wv < 4) asm volatile("s_waitcnt vmcnt(" #N03 ")" ::: "memory");  \
      else        asm volatile("s_waitcnt vmcnt(" #N47 ")" ::: "memory"); }

  f32x4 acc[5][8];
  #pragma unroll
  for (int m = 0; m < 5; ++m)
    #pragma unroll
    for (int n = 0; n < 8; ++n) acc[m][n] = (f32x4){0.f, 0.f, 0.f, 0.f};

  float wA[16], wB[16];
  // prologue FIFO (per wave): W0(16) A0(3|2) W1(16) A1(3|2)
  LOADW(0, wA);
  compiler_fence();
  issueA(0);
  compiler_fence();
  LOADW(1, wB);
  compiler_fence();
  issueA(1);
  compiler_fence();
  WAITV(22, 20);                     // W0 landed; A0,W1,A1 still in flight
  CVTW(0, wA);
  asm volatile("s_waitcnt lgkmcnt(0)" ::: "memory");

  #define BODY(J, WCVT, WLOAD)                                             \
    {                                                                      \
      const int j_ = (J);                                                  \
      if (j_ == 15) { asm volatile("s_waitcnt vmcnt(0)" ::: "memory"); }   \
      else          WAITV(19, 18); /* A(j) done; W/A(j+1) in flight */     \
      block_sync(); /* barrier1: lA[j&1] (all waves), lWbf[j&1] visible */ \
      const char* aB = (const char*)&lA[j_ & 1][0];                        \
      const char* bB = (const char*)&lWbf[j_ & 1][0];                      \
      bf16x8 bfr[8];                                                       \
      _Pragma("unroll")                                                    \
      for (int n = 0; n < 8; ++n) {                                        \
        int col = wn * 128 + n * 16 + lc;                                  \
        bfr[n] = *(const bf16x8*)(bB + ((lg * 256 + col) << 4));           \
      }                                                                    \
      _Pragma("unroll")                                                    \
      for (int m = 0; m < 5; ++m) {                                        \
        int row = wm * 80 + m * 16 + lc;                                   \
        bf16x8 afr = *(const bf16x8*)(aB + row * 64                        \
                       + ((lg ^ ((row >> 1) & 3)) << 4));                  \
        _Pragma("unroll")                                                  \
        for (int n = 0; n < 8; ++n)                                        \
          acc[m][n] = __builtin_amdgcn_mfma_f32_16x16x32_bf16(             \
              afr, bfr[n], acc[m][n], 0, 0, 0);                            \
      }                                                                    \
      if (j_ < 15) {                                                       \
        WAITV(3, 2);            /* W(j+1) regs landed; A(j+1) in flight */ \
        CVTW((j_ + 1) & 1, WCVT);                                          \
      }                                                                    \
      asm volatile("s_waitcnt lgkmcnt(0)" ::: "memory");                   \
      block_sync(); /* barrier2: lWbf[(j+1)&1] published, lA[j&1] free */  \
      if (j_ < 14) {                                                       \
        LOADW(j_ + 2, WLOAD);                                              \
        compiler_fence();                                                  \
        issueA(j_ + 2);                                                    \
        compiler_fence();                                                  \
      }                                                                    \
    }

  for (int jj = 0; jj < 16; jj += 2) {
    BODY(jj,     wB, wA);
    BODY(jj + 1, wA, wB);
  }
  #undef BODY
  #undef LOADW
  #undef CVTW
  #undef WAITV

  // epilogue: bf16 partials, layout [ks][NN][8192]; global col = ntile*256 + ...
  u16* hp = Hpart + (size_t)ks * (NN * 8192) + ntile * 256 + wn * 128;
  #pragma unroll
  for (int m = 0; m < 5; ++m)
    #pragma unroll
    for (int r = 0; r < 4; ++r) {
      const int row = wm * 80 + m * 16 + (lg << 2) + r;
      if (row < NN) {
        #pragma unroll
        for (int n = 0; n < 8; ++n)
          hp[(size_t)row * 8192 + n * 16 + lc] = f2bf(acc[m][n][r]);
      }
    }
}

// ---------------- K2: reduce 8 K-partials + src/dst dots + Hb (bf16) --------
__global__ void srcdstf(const u16* __restrict__ Hp, const float* __restrict__ a_src,
                        const float* __restrict__ a_dst, u16* __restrict__ Hb,
                        float* __restrict__ srcv, float* __restrict__ dstv) {
  const int i = blockIdx.x, h = blockIdx.y;
  const int tid = threadIdx.x;
  const int j4 = tid * 4;
  const u16* base = Hp + (size_t)i * 8192 + h * 1024 + j4;
  float4 v = {0.f, 0.f, 0.f, 0.f};
  #pragma unroll
  for (int q = 0; q < NKS; ++q) {
    bf16x4 p = *(const bf16x4*)(base + (size_t)q * (NN * 8192));
    v.x += bf2f((u16)p[0]); v.y += bf2f((u16)p[1]);
    v.z += bf2f((u16)p[2]); v.w += bf2f((u16)p[3]);
  }
  u16* hb = Hb + ((size_t)h * NN + i) * NHID + j4;
  ushort4 hv = { f2bf(v.x), f2bf(v.y), f2bf(v.z), f2bf(v.w) };
  *(ushort4*)hb = hv;
  const float4 as4 = *(const float4*)(a_src + h * NHID + j4);
  const float4 ad4 = *(const float4*)(a_dst + h * NHID + j4);
  float s = v.x * as4.x + v.y * as4.y + v.z * as4.z + v.w * as4.w;
  float d = v.x * ad4.x + v.y * ad4.y + v.z * ad4.z + v.w * ad4.w;
  s = wave_red(s); d = wave_red(d);
  __shared__ float rb[8];
  const int lane = tid & 63, wid = tid >> 6;
  if (lane == 0) { rb[wid] = s; rb[4 + wid] = d; }
  __syncthreads();
  if (tid == 0) {
    srcv[h * NN + i] = rb[0] + rb[1] + rb[2] + rb[3];
    dstv[h * NN + i] = rb[4] + rb[5] + rb[6] + rb[7];
  }
}

// ---------------- K3a: e = exp(-leakyrelu(src_i+dst_j))*mask, rowsum ----------------
__global__ void ekern(const int* __restrict__ adj, const float* __restrict__ srcv,
                      const float* __restrict__ dstv, u16* __restrict__ eb,
                      float* __restrict__ rowsum) {
  const int i = blockIdx.x, h = blockIdx.y;
  const int n = threadIdx.x;          // 0..319
  float ev = 0.f;
  if (n < NN && adj[i * NN + n] != 0) {
    float lg = srcv[h * NN + i] + dstv[h * NN + n];
    float lr = lg > 0.f ? lg : LALPHA * lg;
    ev = expf(-lr);
  }
  u16 evb = f2bf(ev);
  eb[(size_t)h * NN * 320 + (size_t)i * 320 + n] = evb;
  float evr = wave_red(bf2f(evb));
  __shared__ float rb[5];
  const int lane = threadIdx.x & 63, wid = threadIdx.x >> 6;
  if (lane == 0) rb[wid] = evr;
  __syncthreads();
  if (threadIdx.x == 0) rowsum[h * NN + i] = rb[0] + rb[1] + rb[2] + rb[3] + rb[4];
}

// ---------------- K3b: h2 = elu((e @ H) / rowsum), concat heads ----------------
__global__ __launch_bounds__(512) void gemm2(const u16* __restrict__ eb,
                                             const u16* __restrict__ Hb,
                                             const float* __restrict__ rowsum,
                                             float* __restrict__ h2) {
  __shared__ __align__(16) u16 lA[320 * 72];
  __shared__ __align__(16) u16 lB[32 * 72];
  const int tid  = threadIdx.x;
  const int lane = tid & 63;
  const int wid  = tid >> 6;
  const int wm   = wid >> 1;
  const int wn   = wid & 1;
  const int head = blockIdx.x >> 5;
  const int j0   = (blockIdx.x & 31) * 32;
  f32x4 acc[5];
  #pragma unroll
  for (int m = 0; m < 5; ++m) acc[m] = (f32x4){0.f, 0.f, 0.f, 0.f};

  for (int k0 = 0; k0 < 320; k0 += 64) {
    __syncthreads();
    #pragma unroll
    for (int it = 0; it < 5; ++it) {
      int f   = tid + it * 512;
      int row = f >> 3;
      int kc  = (f & 7) << 3;
      bf16x8 v = {0,0,0,0,0,0,0,0};
      if (row < NN) v = *(const bf16x8*)(eb + (size_t)head * NN * 320 + (size_t)row * 320 + k0 + kc);
      *(bf16x8*)(lA + row * 72 + kc) = v;
    }
    {
      int kk2 = tid >> 3;
      int jc2 = (tid & 7) << 2;
      int k   = k0 + kk2;
      u16 v0 = 0, v1 = 0, v2 = 0, v3 = 0;
      if (k < NN) {
        bf16x4 hv = *(const bf16x4*)(Hb + (size_t)head * NN * NHID + (size_t)k * NHID + j0 + jc2);
        v0 = (u16)hv[0]; v1 = (u16)hv[1]; v2 = (u16)hv[2]; v3 = (u16)hv[3];
      }
      lB[(jc2 + 0) * 72 + kk2] = v0;
      lB[(jc2 + 1) * 72 + kk2] = v1;
      lB[(jc2 + 2) * 72 + kk2] = v2;
      lB[(jc2 + 3) * 72 + kk2] = v3;
    }
    __syncthreads();
    #pragma unroll
    for (int sub = 0; sub < 2; ++sub) {
      int ksub = sub * 32 + ((lane >> 4) << 3);
      bf16x8 bfrag = *(const bf16x8*)(lB + (wn * 16 + (lane & 15)) * 72 + ksub);
      #pragma unroll
      for (int m = 0; m < 5; ++m) {
        int row = wm * 80 + m * 16 + (lane & 15);
        bf16x8 afrag = *(const bf16x8*)(lA + row * 72 + ksub);
        acc[m] = __builtin_amdgcn_mfma_f32_16x16x32_bf16(afrag, bfrag, acc[m], 0, 0, 0);
      }
    }
  }
  const int jj = j0 + wn * 16 + (lane & 15);
  #pragma unroll
  for (int m = 0; m < 5; ++m) {
    #pragma unroll
    for (int r = 0; r < 4; ++r) {
      int row = wm * 80 + m * 16 + ((lane >> 4) << 2) + r;
      if (row < NN) {
        float v = acc[m][r] / rowsum[head * NN + row];
        v = v > 0.f ? v : expm1f(v);                 // elu
        h2[(size_t)row * (NHEADS * NHID) + head * NHID + jj] = v;
      }
    }
  }
}

// ---------------- K4: layer-2 h = h2 @ W_out, plus src2/dst2 ----------------
__global__ void layer2(const float* __restrict__ h2, const float* __restrict__ Wout,
                       const float* __restrict__ aos, const float* __restrict__ aod,
                       float* __restrict__ hL2, float* __restrict__ src2,
                       float* __restrict__ dst2) {
  const int i = blockIdx.x;
  float acc[8] = {0,0,0,0,0,0,0,0};
  for (int k = threadIdx.x; k < NHEADS * NHID; k += 256) {
    float hv = h2[(size_t)i * (NHEADS * NHID) + k];
    const float4 w0 = *(const float4*)(Wout + (size_t)k * 8);
    const float4 w1 = *(const float4*)(Wout + (size_t)k * 8 + 4);
    acc[0] += hv * w0.x; acc[1] += hv * w0.y; acc[2] += hv * w0.z; acc[3] += hv * w0.w;
    acc[4] += hv * w1.x; acc[5] += hv * w1.y; acc[6] += hv * w1.z; acc[7] += hv * w1.w;
  }
  #pragma unroll
  for (int c = 0; c < 8; ++c) acc[c] = wave_red(acc[c]);
  __shared__ float rb[4][8];
  const int lane = threadIdx.x & 63, wid = threadIdx.x >> 6;
  if (lane == 0) {
    #pragma unroll
    for (int c = 0; c < 8; ++c) rb[wid][c] = acc[c];
  }
  __syncthreads();
  if (threadIdx.x == 0) {
    float s = 0.f, d = 0.f;
    #pragma unroll
    for (int c = 0; c < 8; ++c) {
      float v = rb[0][c] + rb[1][c] + rb[2][c] + rb[3][c];
      hL2[i * 8 + c] = v;
      s += v * aos[c];
      d += v * aod[c];
    }
    src2[i] = s; dst2[i] = d;
  }
}

// ---------------- K5a: layer-2 attention + aggregation + elu ----------------
__global__ void out2k(const int* __restrict__ adj, const float* __restrict__ src2,
                      const float* __restrict__ dst2, const float* __restrict__ hL2,
                      float* __restrict__ out2) {
  const int i = blockIdx.x;
  float se = 0.f, acc[8] = {0,0,0,0,0,0,0,0};
  for (int n = threadIdx.x; n < NN; n += 256) {
    if (adj[i * NN + n] != 0) {
      float lg = src2[i] + dst2[n];
      float lr = lg > 0.f ? lg : LALPHA * lg;
      float ev = expf(-lr);
      se += ev;
      #pragma unroll
      for (int c = 0; c < 8; ++c) acc[c] += ev * hL2[n * 8 + c];
    }
  }
  se = wave_red(se);
  #pragma unroll
  for (int c = 0; c < 8; ++c) acc[c] = wave_red(acc[c]);
  __shared__ float rb[4][9];
  const int lane = threadIdx.x & 63, wid = threadIdx.x >> 6;
  if (lane == 0) {
    #pragma unroll
    for (int c = 0; c < 8; ++c) rb[wid][c] = acc[c];
    rb[wid][8] = se;
  }
  __syncthreads();
  if (threadIdx.x == 0) {
    float s = rb[0][8] + rb[1][8] + rb[2][8] + rb[3][8];
    #pragma unroll
    for (int c = 0; c < 8; ++c) {
      float v = (rb[0][c] + rb[1][c] + rb[2][c] + rb[3][c]) / s;
      out2[i * 8 + c] = v > 0.f ? v : expm1f(v);
    }
  }
}

// ---------------- K5b: out = drug @ alpha1 @ mic^T ----------------
__global__ void finalk(const float* __restrict__ out2, const float* __restrict__ alpha1,
                       float* __restrict__ out) {
  int t = blockIdx.x * 256 + threadIdx.x;
  if (t >= NDRUG * NMIC) return;
  int d = t / NMIC, m = t % NMIC;
  const float* dr = out2 + d * 8;
  const float* mi = out2 + (NDRUG + m) * 8;
  float r = 0.f;
  #pragma unroll
  for (int c2 = 0; c2 < 8; ++c2) {
    float a = 0.f;
    #pragma unroll
    for (int c1 = 0; c1 < 8; ++c1) a += dr[c1] * alpha1[c1 * 8 + c2];
    r += a * mi[c2];
  }
  out[t] = r;
}

extern "C" void kernel_launch(void* const* d_in, const int* in_sizes, int n_in,
                              void* d_out, int out_size, void* d_ws, size_t ws_size,
                              hipStream_t stream) {
  const float* x      = (const float*)d_in[0];
  const int*   adj    = (const int*)d_in[1];
  const float* W      = (const float*)d_in[2];
  const float* a_src  = (const float*)d_in[3];
  const float* a_dst  = (const float*)d_in[4];
  const float* W_out  = (const float*)d_in[5];
  const float* aos    = (const float*)d_in[6];
  const float* aod    = (const float*)d_in[7];
  const float* alpha1 = (const float*)d_in[8];
  float* out = (float*)d_out;

  char* p = (char*)d_ws;
  auto take = [&](size_t bytes) {
    char* q = p;
    p += (bytes + 255) & ~(size_t)255;
    return q;
  };
  u16*   xb    = (u16*)  take((size_t)MPAD * NFEAT * 2);            // 2.62 MB
  u16*   Hpart = (u16*)  take((size_t)NKS * NN * 8192 * 2);         // 35.4 MB (bf16 partials)
  u16*   Hb    = (u16*)  take((size_t)NHEADS * NN * NHID * 2);      // 4.42 MB
  float* srcv  = (float*)take((size_t)NHEADS * NN * 4);
  float* dstv  = (float*)take((size_t)NHEADS * NN * 4);
  // --- aliases into Hpart (dead after srcdstf) ---
  char*  hbase = (char*)Hpart;
  float* h2    = (float*)hbase;                                     // 8.85 MB @ +0
  u16*   eb    = (u16*)  (hbase + 10000000);                        // 1.38 MB
  float* rs    = (float*)(hbase + 11500000);
  float* hL2   = (float*)(hbase + 11600000);
  float* s2    = (float*)(hbase + 11700000);
  float* d2    = (float*)(hbase + 11800000);
  float* o2    = (float*)(hbase + 11900000);

  cvt_x<<<640, 256, 0, stream>>>(x, xb);
  gemm1<<<256, 512, 0, stream>>>(xb, W, Hpart);
  srcdstf<<<dim3(NN, NHEADS), 256, 0, stream>>>(Hpart, a_src, a_dst, Hb, srcv, dstv);
  ekern<<<dim3(NN, NHEADS), 320, 0, stream>>>(adj, srcv, dstv, eb, rs);
  gemm2<<<256, 512, 0, stream>>>(eb, Hb, rs, h2);
  layer2<<<NN, 256, 0, stream>>>(h2, W_out, aos, aod, hL2, s2, d2);
  out2k<<<NN, 256, 0, stream>>>(adj, s2, d2, hL2, o2);
  finalk<<<65, 256, 0, stream>>>(o2, alpha1, out);
}

// Round 13
// 92.402 us; speedup vs baseline: 1.1938x; 1.0283x over previous
//
#include <hip/hip_runtime.h>
#include <hip/hip_bf16.h>

#define NN     270
#define MPAD   320
#define NFEAT  4096
#define NHID   1024
#define NHEADS 8
#define NCLS   8
#define NDRUG  175
#define NMIC   95
#define LALPHA 0.2f
#define NKS    8          // K-chunks in gemm1

typedef unsigned short u16;
typedef unsigned int   u32;
typedef __attribute__((ext_vector_type(8))) short bf16x8;
typedef __attribute__((ext_vector_type(4))) short bf16x4;
typedef __attribute__((ext_vector_type(4))) float f32x4;

static __device__ __forceinline__ u16 f2bf(float f) {
  union { float f; u32 u; } v; v.f = f;
  u32 r = v.u + 0x7FFFu + ((v.u >> 16) & 1u);   // round-to-nearest-even
  return (u16)(r >> 16);
}
static __device__ __forceinline__ float bf2f(u16 b) {
  union { u32 u; float f; } v; v.u = ((u32)b) << 16;
  return v.f;
}
static __device__ __forceinline__ float wave_red(float v) {
  #pragma unroll
  for (int o = 32; o > 0; o >>= 1) v += __shfl_down(v, o, 64);
  return v;
}
static __device__ __forceinline__ void block_sync() {
  asm volatile("" ::: "memory");
  __builtin_amdgcn_s_barrier();
  asm volatile("" ::: "memory");
}
#define GLOAD16(g, l) __builtin_amdgcn_global_load_lds(                    \
    (__attribute__((address_space(1))) void*)(g),                          \
    (__attribute__((address_space(3))) void*)(l), 16, 0, 0)

// ---------------- K0: x (f32) -> xb (bf16), zero-padded to 320 rows ----------
__global__ void cvt_x(const float* __restrict__ x, u16* __restrict__ xb) {
  int i = (blockIdx.x * 256 + threadIdx.x) * 8;
  if (i >= MPAD * NFEAT) return;
  int row = i >> 12;                 // / NFEAT
  uint4 o = {0, 0, 0, 0};
  if (row < NN) {
    float4 a = *(const float4*)(x + i);
    float4 b = *(const float4*)(x + i + 4);
    o.x = (u32)f2bf(a.x) | ((u32)f2bf(a.y) << 16);
    o.y = (u32)f2bf(a.z) | ((u32)f2bf(a.w) << 16);
    o.z = (u32)f2bf(b.x) | ((u32)f2bf(b.y) << 16);
    o.w = (u32)f2bf(b.z) | ((u32)f2bf(b.w) << 16);
  }
  *(uint4*)(xb + i) = o;
}

// ---------------- K1: Hpart[ks] = x @ W[kchunk ks] ----------------
// Geometry: 256 blocks = 32 n-tiles (BN=256) x 8 K-chunks (K=512); BM=320 ->
// W staged EXACTLY once (134 MB), A 32x from L2 (84 MB).  W via global_load_lds
// (the 12-13 B/cy/CU path) -> lWf[2] linear -> in-LDS transpose+cvt -> lWbf[2].
// RACE INVARIANTS:
//  (1) [r10 lesson] transposeW(t) reads lWf written by OTHER waves' glds ->
//      W(t) must be certified landed + barrier'd before the transpose.
//  (2) [r12 lesson] issueW(t+2) OVERWRITES lWf[t&1]; it may only be issued
//      after ALL waves' transposeW(t) reads are drained (lgkmcnt(0)+barrier).
//      r12's prologue violated this: issueW(2) was in the initial glds burst,
//      racing transposeW(0). Fixed: issueW(2) moved after a prologue
//      transpose-drain barrier.
// Steady loop (audited): top WAITV(7|6) leaves [A(j+1), W(j+2)] -> certifies
// A(j)+W(j+1); barrier1; MFMA + transposeW(j+1) (no mid-iter wait);
// lgkmcnt(0); barrier2; issueA(j+2); issueW(j+3) [overwrites lWf[(j+1)&1],
// dead after barrier2]. Tail: WAITV(3|2) at j=14, vmcnt(0) at j=15.
__global__ __launch_bounds__(512) void gemm1(const u16* __restrict__ xb,
                                             const float* __restrict__ W,
                                             u16* __restrict__ Hpart) {
  __shared__ __align__(16) u16   lA[2][MPAD * 32];    // 2 x 20 KB [row][64B] swz
  __shared__ __align__(16) float lWf[2][32 * 256];    // 2 x 32 KB [k][col] linear
  __shared__ __align__(16) u32   lWbf[2][4096];       // 2 x 16 KB [kb(4)][col(256)][16B]
  const int tid  = threadIdx.x;
  const int lane = tid & 63;
  const int wv   = tid >> 6;
  const int wm   = wv >> 1;          // 80-row band
  const int wn   = wv & 1;           // 128-col band
  const int lc   = lane & 15;
  const int lg   = lane >> 4;
  const int ks    = blockIdx.x & 7;          // same-A blocks share an XCD
  const int ntile = blockIdx.x >> 3;         // 0..31
  const int head  = ntile >> 2;
  const int jB    = (ntile & 3) * 256;       // within-head col base (W only)

  // ---- A staging: 320x32 bf16 = 20 KB; 3 glds (waves 0-3) / 2 (waves 4-7) ----
  auto issueA = [&](int j) {
    char* lbase = (char*)&lA[j & 1][0];
    #pragma unroll
    for (int q = 0; q < 2; ++q) {
      int c = q * 512 + tid;
      int row = c >> 2, p = c & 3;
      const char* g = (const char*)xb + (size_t)row * 8192 + ks * 1024 + j * 64
                      + ((p ^ ((row >> 1) & 3)) << 4);
      GLOAD16(g, lbase + c * 16);
    }
    if (tid < 256) {
      int c = 1024 + tid;
      int row = c >> 2, p = c & 3;
      const char* g = (const char*)xb + (size_t)row * 8192 + ks * 1024 + j * 64
                      + ((p ^ ((row >> 1) & 3)) << 4);
      GLOAD16(g, lbase + c * 16);
    }
  };

  // ---- W staging: 32k x 256 cols f32 = 32 KB = 4 x 16B glds per thread ----
  const char* gW0 = (const char*)(W + (size_t)head * 4194304
                                    + (size_t)ks * 512 * 1024 + jB);
  auto issueW = [&](int j) {
    char* l0 = (char*)&lWf[j & 1][0] + tid * 16;
    const char* g0 = gW0 + (size_t)j * 131072 + (tid >> 6) * 4096 + (lane << 4);
    #pragma unroll
    for (int q = 0; q < 4; ++q)        // q -> 8 k-rows = 32768B glob, 8192B lds
      GLOAD16(g0 + q * 32768, l0 + q * 8192);
  };

  // ---- in-LDS transpose+cvt: lWf[t&1] f32 [k][col] -> lWbf[t&1] bf16 frags --
  const int wcol = tid & 255;
  const int wkb0 = (tid >> 8) * 2;
  auto transposeW = [&](int t) {
    const float* wf = &lWf[t & 1][0];
    u32* dst = &lWbf[t & 1][0];
    #pragma unroll
    for (int i2 = 0; i2 < 2; ++i2) {
      int kb = wkb0 + i2;
      float f[8];
      #pragma unroll
      for (int q = 0; q < 8; ++q) f[q] = wf[(kb * 8 + q) * 256 + wcol];
      uint4 o;
      o.x = (u32)f2bf(f[0]) | ((u32)f2bf(f[1]) << 16);
      o.y = (u32)f2bf(f[2]) | ((u32)f2bf(f[3]) << 16);
      o.z = (u32)f2bf(f[4]) | ((u32)f2bf(f[5]) << 16);
      o.w = (u32)f2bf(f[6]) | ((u32)f2bf(f[7]) << 16);
      *(uint4*)((char*)dst + (kb * 256 + wcol) * 16) = o;
    }
  };

  // wave-uniform counted waits (waves 0-3 have 1 extra A glds per batch)
  #define WAITV(N03, N47)                                                  \
    do {                                                                   \
      if (wv < 4) asm volatile("s_waitcnt vmcnt(" #N03 ")" ::: "memory");  \
      else        asm volatile("s_waitcnt vmcnt(" #N47 ")" ::: "memory");  \
    } while (0)

  f32x4 acc[5][8];
  #pragma unroll
  for (int m = 0; m < 5; ++m)
    #pragma unroll
    for (int n = 0; n < 8; ++n) acc[m][n] = (f32x4){0.f, 0.f, 0.f, 0.f};

  // prologue FIFO (per wave): W0(4) W1(4) A0(3|2) A1(3|2)
  issueW(0); issueW(1); issueA(0); issueA(1);
  WAITV(10, 8);                      // own W0 landed; W1,A0,A1 in flight
  block_sync();                      // ALL waves' W0 writes landed & visible
  transposeW(0);
  asm volatile("s_waitcnt lgkmcnt(0)" ::: "memory");
  block_sync();                      // ALL waves done reading lWf[0]
  issueW(2);                         // NOW safe to overwrite lWf[0] (r12 fix)

  for (int j = 0; j < 16; ++j) {
    // top: certify A(j) AND W(j+1) landed (leaves A(j+1), W(j+2) in flight)
    if (j <= 13) {
      WAITV(7, 6);
    } else if (j == 14) {
      WAITV(3, 2);                   // leaves A(15) only
    } else {
      asm volatile("s_waitcnt vmcnt(0)" ::: "memory");
    }
    block_sync();   // barrier1: lA[j&1], lWbf[j&1], and lWf[(j+1)&1] all visible

    const char* aB = (const char*)&lA[j & 1][0];
    const char* bB = (const char*)&lWbf[j & 1][0];
    bf16x8 bfr[8];
    #pragma unroll
    for (int n = 0; n < 8; ++n) {
      int col = wn * 128 + n * 16 + lc;
      bfr[n] = *(const bf16x8*)(bB + ((lg * 256 + col) << 4));
    }
    #pragma unroll
    for (int m = 0; m < 5; ++m) {
      int row = wm * 80 + m * 16 + lc;
      bf16x8 afr = *(const bf16x8*)(aB + row * 64 + ((lg ^ ((row >> 1) & 3)) << 4));
      #pragma unroll
      for (int n = 0; n < 8; ++n)
        acc[m][n] = __builtin_amdgcn_mfma_f32_16x16x32_bf16(afr, bfr[n], acc[m][n], 0, 0, 0);
    }
    if (j < 15) transposeW(j + 1);   // W(j+1) landed pre-barrier1: race-free
    asm volatile("s_waitcnt lgkmcnt(0)" ::: "memory");
    block_sync();   // barrier2: lWbf[(j+1)&1] published; lWf[(j+1)&1], lA[j&1] free
    if (j <= 13) issueA(j + 2);
    if (j <= 12) issueW(j + 3);      // overwrites lWf[(j+1)&1] — dead after barrier2
  }
  #undef WAITV

  // epilogue: bf16 partials, layout [ks][NN][8192]; global col = ntile*256 + ...
  u16* hp = Hpart + (size_t)ks * (NN * 8192) + ntile * 256 + wn * 128;
  #pragma unroll
  for (int m = 0; m < 5; ++m)
    #pragma unroll
    for (int r = 0; r < 4; ++r) {
      const int row = wm * 80 + m * 16 + (lg << 2) + r;
      if (row < NN) {
        #pragma unroll
        for (int n = 0; n < 8; ++n)
          hp[(size_t)row * 8192 + n * 16 + lc] = f2bf(acc[m][n][r]);
      }
    }
}

// ---------------- K2: reduce 8 K-partials + src/dst dots + Hb (bf16) --------
__global__ void srcdstf(const u16* __restrict__ Hp, const float* __restrict__ a_src,
                        const float* __restrict__ a_dst, u16* __restrict__ Hb,
                        float* __restrict__ srcv, float* __restrict__ dstv) {
  const int i = blockIdx.x, h = blockIdx.y;
  const int tid = threadIdx.x;
  const int j4 = tid * 4;
  const u16* base = Hp + (size_t)i * 8192 + h * 1024 + j4;
  float4 v = {0.f, 0.f, 0.f, 0.f};
  #pragma unroll
  for (int q = 0; q < NKS; ++q) {
    bf16x4 p = *(const bf16x4*)(base + (size_t)q * (NN * 8192));
    v.x += bf2f((u16)p[0]); v.y += bf2f((u16)p[1]);
    v.z += bf2f((u16)p[2]); v.w += bf2f((u16)p[3]);
  }
  u16* hb = Hb + ((size_t)h * NN + i) * NHID + j4;
  ushort4 hv = { f2bf(v.x), f2bf(v.y), f2bf(v.z), f2bf(v.w) };
  *(ushort4*)hb = hv;
  const float4 as4 = *(const float4*)(a_src + h * NHID + j4);
  const float4 ad4 = *(const float4*)(a_dst + h * NHID + j4);
  float s = v.x * as4.x + v.y * as4.y + v.z * as4.z + v.w * as4.w;
  float d = v.x * ad4.x + v.y * ad4.y + v.z * ad4.z + v.w * ad4.w;
  s = wave_red(s); d = wave_red(d);
  __shared__ float rb[8];
  const int lane = tid & 63, wid = tid >> 6;
  if (lane == 0) { rb[wid] = s; rb[4 + wid] = d; }
  __syncthreads();
  if (tid == 0) {
    srcv[h * NN + i] = rb[0] + rb[1] + rb[2] + rb[3];
    dstv[h * NN + i] = rb[4] + rb[5] + rb[6] + rb[7];
  }
}

// ---------------- K3a: e = exp(-leakyrelu(src_i+dst_j))*mask, rowsum ----------------
__global__ void ekern(const int* __restrict__ adj, const float* __restrict__ srcv,
                      const float* __restrict__ dstv, u16* __restrict__ eb,
                      float* __restrict__ rowsum) {
  const int i = blockIdx.x, h = blockIdx.y;
  const int n = threadIdx.x;          // 0..319
  float ev = 0.f;
  if (n < NN && adj[i * NN + n] != 0) {
    float lg = srcv[h * NN + i] + dstv[h * NN + n];
    float lr = lg > 0.f ? lg : LALPHA * lg;
    ev = expf(-lr);
  }
  u16 evb = f2bf(ev);
  eb[(size_t)h * NN * 320 + (size_t)i * 320 + n] = evb;
  float evr = wave_red(bf2f(evb));
  __shared__ float rb[5];
  const int lane = threadIdx.x & 63, wid = threadIdx.x >> 6;
  if (lane == 0) rb[wid] = evr;
  __syncthreads();
  if (threadIdx.x == 0) rowsum[h * NN + i] = rb[0] + rb[1] + rb[2] + rb[3] + rb[4];
}

// ---------------- K3b: h2 = elu((e @ H) / rowsum), concat heads ----------------
__global__ __launch_bounds__(512) void gemm2(const u16* __restrict__ eb,
                                             const u16* __restrict__ Hb,
                                             const float* __restrict__ rowsum,
                                             float* __restrict__ h2) {
  __shared__ __align__(16) u16 lA[320 * 72];
  __shared__ __align__(16) u16 lB[32 * 72];
  const int tid  = threadIdx.x;
  const int lane = tid & 63;
  const int wid  = tid >> 6;
  const int wm   = wid >> 1;
  const int wn   = wid & 1;
  const int head = blockIdx.x >> 5;
  const int j0   = (blockIdx.x & 31) * 32;
  f32x4 acc[5];
  #pragma unroll
  for (int m = 0; m < 5; ++m) acc[m] = (f32x4){0.f, 0.f, 0.f, 0.f};

  for (int k0 = 0; k0 < 320; k0 += 64) {
    __syncthreads();
    #pragma unroll
    for (int it = 0; it < 5; ++it) {
      int f   = tid + it * 512;
      int row = f >> 3;
      int kc  = (f & 7) << 3;
      bf16x8 v = {0,0,0,0,0,0,0,0};
      if (row < NN) v = *(const bf16x8*)(eb + (size_t)head * NN * 320 + (size_t)row * 320 + k0 + kc);
      *(bf16x8*)(lA + row * 72 + kc) = v;
    }
    {
      int kk2 = tid >> 3;
      int jc2 = (tid & 7) << 2;
      int k   = k0 + kk2;
      u16 v0 = 0, v1 = 0, v2 = 0, v3 = 0;
      if (k < NN) {
        bf16x4 hv = *(const bf16x4*)(Hb + (size_t)head * NN * NHID + (size_t)k * NHID + j0 + jc2);
        v0 = (u16)hv[0]; v1 = (u16)hv[1]; v2 = (u16)hv[2]; v3 = (u16)hv[3];
      }
      lB[(jc2 + 0) * 72 + kk2] = v0;
      lB[(jc2 + 1) * 72 + kk2] = v1;
      lB[(jc2 + 2) * 72 + kk2] = v2;
      lB[(jc2 + 3) * 72 + kk2] = v3;
    }
    __syncthreads();
    #pragma unroll
    for (int sub = 0; sub < 2; ++sub) {
      int ksub = sub * 32 + ((lane >> 4) << 3);
      bf16x8 bfrag = *(const bf16x8*)(lB + (wn * 16 + (lane & 15)) * 72 + ksub);
      #pragma unroll
      for (int m = 0; m < 5; ++m) {
        int row = wm * 80 + m * 16 + (lane & 15);
        bf16x8 afrag = *(const bf16x8*)(lA + row * 72 + ksub);
        acc[m] = __builtin_amdgcn_mfma_f32_16x16x32_bf16(afrag, bfrag, acc[m], 0, 0, 0);
      }
    }
  }
  const int jj = j0 + wn * 16 + (lane & 15);
  #pragma unroll
  for (int m = 0; m < 5; ++m) {
    #pragma unroll
    for (int r = 0; r < 4; ++r) {
      int row = wm * 80 + m * 16 + ((lane >> 4) << 2) + r;
      if (row < NN) {
        float v = acc[m][r] / rowsum[head * NN + row];
        v = v > 0.f ? v : expm1f(v);                 // elu
        h2[(size_t)row * (NHEADS * NHID) + head * NHID + jj] = v;
      }
    }
  }
}

// ---------------- K4: layer-2 h = h2 @ W_out, plus src2/dst2 ----------------
__global__ void layer2(const float* __restrict__ h2, const float* __restrict__ Wout,
                       const float* __restrict__ aos, const float* __restrict__ aod,
                       float* __restrict__ hL2, float* __restrict__ src2,
                       float* __restrict__ dst2) {
  const int i = blockIdx.x;
  float acc[8] = {0,0,0,0,0,0,0,0};
  for (int k = threadIdx.x; k < NHEADS * NHID; k += 256) {
    float hv = h2[(size_t)i * (NHEADS * NHID) + k];
    const float4 w0 = *(const float4*)(Wout + (size_t)k * 8);
    const float4 w1 = *(const float4*)(Wout + (size_t)k * 8 + 4);
    acc[0] += hv * w0.x; acc[1] += hv * w0.y; acc[2] += hv * w0.z; acc[3] += hv * w0.w;
    acc[4] += hv * w1.x; acc[5] += hv * w1.y; acc[6] += hv * w1.z; acc[7] += hv * w1.w;
  }
  #pragma unroll
  for (int c = 0; c < 8; ++c) acc[c] = wave_red(acc[c]);
  __shared__ float rb[4][8];
  const int lane = threadIdx.x & 63, wid = threadIdx.x >> 6;
  if (lane == 0) {
    #pragma unroll
    for (int c = 0; c < 8; ++c) rb[wid][c] = acc[c];
  }
  __syncthreads();
  if (threadIdx.x == 0) {
    float s = 0.f, d = 0.f;
    #pragma unroll
    for (int c = 0; c < 8; ++c) {
      float v = rb[0][c] + rb[1][c] + rb[2][c] + rb[3][c];
      hL2[i * 8 + c] = v;
      s += v * aos[c];
      d += v * aod[c];
    }
    src2[i] = s; dst2[i] = d;
  }
}

// ---------------- K5a: layer-2 attention + aggregation + elu ----------------
__global__ void out2k(const int* __restrict__ adj, const float* __restrict__ src2,
                      const float* __restrict__ dst2, const float* __restrict__ hL2,
                      float* __restrict__ out2) {
  const int i = blockIdx.x;
  float se = 0.f, acc[8] = {0,0,0,0,0,0,0,0};
  for (int n = threadIdx.x; n < NN; n += 256) {
    if (adj[i * NN + n] != 0) {
      float lg = src2[i] + dst2[n];
      float lr = lg > 0.f ? lg : LALPHA * lg;
      float ev = expf(-lr);
      se += ev;
      #pragma unroll
      for (int c = 0; c < 8; ++c) acc[c] += ev * hL2[n * 8 + c];
    }
  }
  se = wave_red(se);
  #pragma unroll
  for (int c = 0; c < 8; ++c) acc[c] = wave_red(acc[c]);
  __shared__ float rb[4][9];
  const int lane = threadIdx.x & 63, wid = threadIdx.x >> 6;
  if (lane == 0) {
    #pragma unroll
    for (int c = 0; c < 8; ++c) rb[wid][c] = acc[c];
    rb[wid][8] = se;
  }
  __syncthreads();
  if (threadIdx.x == 0) {
    float s = rb[0][8] + rb[1][8] + rb[2][8] + rb[3][8];
    #pragma unroll
    for (int c = 0; c < 8; ++c) {
      float v = (rb[0][c] + rb[1][c] + rb[2][c] + rb[3][c]) / s;
      out2[i * 8 + c] = v > 0.f ? v : expm1f(v);
    }
  }
}

// ---------------- K5b: out = drug @ alpha1 @ mic^T ----------------
__global__ void finalk(const float* __restrict__ out2, const float* __restrict__ alpha1,
                       float* __restrict__ out) {
  int t = blockIdx.x * 256 + threadIdx.x;
  if (t >= NDRUG * NMIC) return;
  int d = t / NMIC, m = t % NMIC;
  const float* dr = out2 + d * 8;
  const float* mi = out2 + (NDRUG + m) * 8;
  float r = 0.f;
  #pragma unroll
  for (int c2 = 0; c2 < 8; ++c2) {
    float a = 0.f;
    #pragma unroll
    for (int c1 = 0; c1 < 8; ++c1) a += dr[c1] * alpha1[c1 * 8 + c2];
    r += a * mi[c2];
  }
  out[t] = r;
}

extern "C" void kernel_launch(void* const* d_in, const int* in_sizes, int n_in,
                              void* d_out, int out_size, void* d_ws, size_t ws_size,
                              hipStream_t stream) {
  const float* x      = (const float*)d_in[0];
  const int*   adj    = (const int*)d_in[1];
  const float* W      = (const float*)d_in[2];
  const float* a_src  = (const float*)d_in[3];
  const float* a_dst  = (const float*)d_in[4];
  const float* W_out  = (const float*)d_in[5];
  const float* aos    = (const float*)d_in[6];
  const float* aod    = (const float*)d_in[7];
  const float* alpha1 = (const float*)d_in[8];
  float* out = (float*)d_out;

  char* p = (char*)d_ws;
  auto take = [&](size_t bytes) {
    char* q = p;
    p += (bytes + 255) & ~(size_t)255;
    return q;
  };
  u16*   xb    = (u16*)  take((size_t)MPAD * NFEAT * 2);            // 2.62 MB
  u16*   Hpart = (u16*)  take((size_t)NKS * NN * 8192 * 2);         // 35.4 MB (bf16 partials)
  u16*   Hb    = (u16*)  take((size_t)NHEADS * NN * NHID * 2);      // 4.42 MB
  float* srcv  = (float*)take((size_t)NHEADS * NN * 4);
  float* dstv  = (float*)take((size_t)NHEADS * NN * 4);
  // --- aliases into Hpart (dead after srcdstf) ---
  char*  hbase = (char*)Hpart;
  float* h2    = (float*)hbase;                                     // 8.85 MB @ +0
  u16*   eb    = (u16*)  (hbase + 10000000);                        // 1.38 MB
  float* rs    = (float*)(hbase + 11500000);
  float* hL2   = (float*)(hbase + 11600000);
  float* s2    = (float*)(hbase + 11700000);
  float* d2    = (float*)(hbase + 11800000);
  float* o2    = (float*)(hbase + 11900000);

  cvt_x<<<640, 256, 0, stream>>>(x, xb);
  gemm1<<<256, 512, 0, stream>>>(xb, W, Hpart);
  srcdstf<<<dim3(NN, NHEADS), 256, 0, stream>>>(Hpart, a_src, a_dst, Hb, srcv, dstv);
  ekern<<<dim3(NN, NHEADS), 320, 0, stream>>>(adj, srcv, dstv, eb, rs);
  gemm2<<<256, 512, 0, stream>>>(eb, Hb, rs, h2);
  layer2<<<NN, 256, 0, stream>>>(h2, W_out, aos, aod, hL2, s2, d2);
  out2k<<<NN, 256, 0, stream>>>(adj, s2, d2, hL2, o2);
  finalk<<<65, 256, 0, stream>>>(o2, alpha1, out);
}